// Round 13
// baseline (44.988 us; speedup 1.0000x reference)
//
#include <hip/hip_runtime.h>
#include <hip/hip_bf16.h>

#define NB 16
#define NN 256
#define NH 8
#define ND 64
#define NT 5
#define HD 512   // NH*ND

typedef __bf16 bf16x8 __attribute__((ext_vector_type(8)));
typedef __bf16 bf16x4 __attribute__((ext_vector_type(4)));
typedef float  f32x4  __attribute__((ext_vector_type(4)));
typedef int    i32x4  __attribute__((ext_vector_type(4)));

__device__ __forceinline__ bf16x8 cvt8(f32x4 a, f32x4 b) {
    bf16x8 r;
    r[0] = (__bf16)a[0]; r[1] = (__bf16)a[1]; r[2] = (__bf16)a[2]; r[3] = (__bf16)a[3];
    r[4] = (__bf16)b[0]; r[5] = (__bf16)b[1]; r[6] = (__bf16)b[2]; r[7] = (__bf16)b[3];
    return r;
}

// fire-and-forget global->LDS: lane l writes LDS[base + l*16]; src addr is per-lane.
__device__ __forceinline__ void stage16(const void* g, void* l) {
    __builtin_amdgcn_global_load_lds(
        (const __attribute__((address_space(1))) void*)g,
        (__attribute__((address_space(3))) void*)l,
        16, 0, 0);
}

// Transpose a[(h*64+dd)*64*5 + e*5 + t] (fp32) -> wt[h][t][e][dd] (bf16).
__global__ void prep_w_kernel(const float* __restrict__ a, __bf16* __restrict__ wt) {
    int idx = blockIdx.x * 256 + threadIdx.x;
    if (idx >= NH * ND * ND * NT) return;
    int t  = idx % NT;
    int e  = (idx / NT) % ND;
    int dd = (idx / (NT * ND)) % ND;
    int h  = idx / (NT * ND * ND);
    wt[(((h * NT + t) * ND + e) * ND) + dd] = (__bf16)a[idx];
}

// ================= fused: block = (b, h, j-half); loops all 16 i-tiles =================
// Stage W (all 5 t) + D once; double-buffered src/edge staging under compute.
// All LDS index/swizzle patterns identical to R12's verified kernels.
__global__ __launch_bounds__(256, 1) void mhea_fused(
    const float* __restrict__ src, const float* __restrict__ dst,
    const __bf16* __restrict__ wt, const int* __restrict__ edges,
    float* __restrict__ out)
{
    // W: [t][e(64) x 128B], 16B-chunk c holds global chunk c^(e&7)    (40 KB)
    __shared__ alignas(16) __bf16 Wl[NT * ND * ND];
    // D: rows j(128) x 256B, chunk c holds global c^(j&7)             (32 KB)
    __shared__ alignas(16) float  Dl[128 * ND];
    // S: dbuf, rows i(16) x 256B, chunk c holds global c^(i&7)        (2 x 4 KB)
    __shared__ alignas(16) float  Sl[2][16 * ND];
    // E: dbuf, rows i(16) x 512B, chunk c holds global c^(i&7)        (2 x 8 KB)
    __shared__ alignas(16) int    El[2][16 * 128];
    // P: [t][i(16)][e(64)] bf16, elem ^ ((i&7)<<3)                    (10 KB)
    __shared__ alignas(16) __bf16 Pl[NT * 16 * ND];

    // XCD-chunked decode: XCD x gets 32 consecutive wgs = 2 complete b's.
    const int bid = blockIdx.x;
    const int wg  = (bid & 7) * 32 + (bid >> 3);    // bijective, 256 = 8*32
    const int b   = wg >> 4;
    const int h   = (wg >> 1) & 7;
    const int jh  = wg & 1;
    const int j0  = jh * 128;

    const int tid = threadIdx.x;
    const int w   = tid >> 6;    // wave 0..3: phase-1 e-tile, phase-2 j-pair
    const int l   = tid & 63;
    const int il  = l & 15;
    const int kg  = l >> 4;      // lane k-group 0..3

    // ---------------- prologue staging: W (40), D (32), S[0] (4), E[0] (8) ----------------
    {
        const __bf16* wbase = wt + (size_t)(h * NT) * ND * ND;
        #pragma unroll
        for (int k = 0; k < 10; ++k) {           // W: 40 x 1KB, 10/wave
            const int idx  = w * 10 + k;         // 0..39
            const int t    = idx >> 3;
            const int idx8 = idx & 7;
            const int e    = idx8 * 8 + (l >> 3);
            const int c    = (l & 7) ^ (e & 7);
            stage16(wbase + ((size_t)t * ND + e) * ND + c * 8,
                    &Wl[t * 4096 + idx8 * 512]);
        }
        #pragma unroll
        for (int k = 0; k < 8; ++k) {            // D: 32 x 1KB, 8/wave
            const int idx  = w * 8 + k;
            const int jloc = idx * 4 + (l >> 4);
            const int c    = (l & 15) ^ (jloc & 7);
            stage16(dst + ((size_t)(b * NN + j0 + jloc)) * HD + h * ND + c * 4,
                    &Dl[idx * 256]);
        }
        {                                        // S[0]: 4 x 1KB, 1/wave
            const int row = w * 4 + (l >> 4);
            const int c   = (l & 15) ^ (row & 7);
            stage16(src + ((size_t)(b * NN + row)) * HD + h * ND + c * 4,
                    &Sl[0][w * 256]);
        }
        #pragma unroll
        for (int k = 0; k < 2; ++k) {            // E[0]: 8 x 1KB, 2/wave
            const int idx = w * 2 + k;
            const int row = idx * 2 + (l >> 5);
            const int c   = (l & 31) ^ (row & 7);
            stage16(edges + ((size_t)(b * NN + row)) * NN + j0 + c * 4,
                    &El[0][idx * 256]);
        }
    }

    __syncthreads();   // vmcnt(0) drain: W, D, S[0], E[0] all resident

    // W-frags held in registers for the whole block (wave's e-tile = w, all 5 t)
    bf16x8 wa[NT][2];
    #pragma unroll
    for (int t = 0; t < NT; ++t)
        #pragma unroll
        for (int ks = 0; ks < 2; ++ks)
            wa[t][ks] = *reinterpret_cast<const bf16x8*>(
                &Wl[t * 4096 + (w * 16 + il) * ND + (((ks * 4 + kg) ^ (il & 7)) << 3)]);

    // ---------------- main loop over 16 i-tiles ----------------
    for (int k = 0; k < 16; ++k) {
        const int cb = k & 1;
        const int nb = cb ^ 1;

        // a) stage next i-tile's src + edges (overlaps with phase 1)
        if (k < 15) {
            const int i1 = (k + 1) * 16;
            {
                const int row = w * 4 + (l >> 4);
                const int c   = (l & 15) ^ (row & 7);
                stage16(src + ((size_t)(b * NN + i1 + row)) * HD + h * ND + c * 4,
                        &Sl[nb][w * 256]);
            }
            #pragma unroll
            for (int kk = 0; kk < 2; ++kk) {
                const int idx = w * 2 + kk;
                const int row = idx * 2 + (l >> 5);
                const int c   = (l & 31) ^ (row & 7);
                stage16(edges + ((size_t)(b * NN + i1 + row)) * NN + j0 + c * 4,
                        &El[nb][idx * 256]);
            }
        }

        // b) phase 1: P_t[i,e] for this i-tile (wave's e-tile = w)
        {
            f32x4 a0 = *reinterpret_cast<const f32x4*>(&Sl[cb][il * ND + (((2 * kg + 0) ^ (il & 7)) << 2)]);
            f32x4 a1 = *reinterpret_cast<const f32x4*>(&Sl[cb][il * ND + (((2 * kg + 1) ^ (il & 7)) << 2)]);
            f32x4 a2 = *reinterpret_cast<const f32x4*>(&Sl[cb][il * ND + (((8 + 2 * kg) ^ (il & 7)) << 2)]);
            f32x4 a3 = *reinterpret_cast<const f32x4*>(&Sl[cb][il * ND + (((9 + 2 * kg) ^ (il & 7)) << 2)]);
            bf16x8 bf0 = cvt8(a0, a1);
            bf16x8 bf1 = cvt8(a2, a3);
            #pragma unroll
            for (int t = 0; t < NT; ++t) {
                // A = W^T rows (m=e), B = src (n=i): lane holds e=w*16+kg*4+r, i=il
                f32x4 pacc = {0.f, 0.f, 0.f, 0.f};
                pacc = __builtin_amdgcn_mfma_f32_16x16x32_bf16(wa[t][0], bf0, pacc, 0, 0, 0);
                pacc = __builtin_amdgcn_mfma_f32_16x16x32_bf16(wa[t][1], bf1, pacc, 0, 0, 0);
                bf16x4 pk;
                pk[0] = (__bf16)pacc[0];
                pk[1] = (__bf16)pacc[1];
                pk[2] = (__bf16)pacc[2];
                pk[3] = (__bf16)pacc[3];
                const int elem = (w * 16 + kg * 4) ^ ((il & 7) << 3);
                *reinterpret_cast<bf16x4*>(&Pl[t * 1024 + il * ND + elem]) = pk;
            }
        }

        // c) barrier: P visible; next-tile staging drained (hidden under phase 1)
        __syncthreads();

        // d) phase 2: this wave's 2 j-tiles (j = w*32 .. w*32+31)
        {
            bf16x8 pa[NT][2];
            #pragma unroll
            for (int t = 0; t < NT; ++t)
                #pragma unroll
                for (int ks = 0; ks < 2; ++ks)
                    pa[t][ks] = *reinterpret_cast<const bf16x8*>(
                        &Pl[t * 1024 + il * ND + (((ks * 4 + kg) ^ (il & 7)) << 3)]);

            float* obase = out + ((size_t)(b * NH + h) * NN + k * 16 + il) * NN + j0;

            #pragma unroll
            for (int jt2 = 0; jt2 < 2; ++jt2) {
                const int jt   = w * 2 + jt2;    // local j-tile 0..7
                const int jrow = jt * 16 + il;
                f32x4 q0 = *reinterpret_cast<const f32x4*>(&Dl[jrow * ND + (((2 * kg + 0) ^ (il & 7)) << 2)]);
                f32x4 q1 = *reinterpret_cast<const f32x4*>(&Dl[jrow * ND + (((2 * kg + 1) ^ (il & 7)) << 2)]);
                f32x4 q2 = *reinterpret_cast<const f32x4*>(&Dl[jrow * ND + (((8 + 2 * kg) ^ (il & 7)) << 2)]);
                f32x4 q3 = *reinterpret_cast<const f32x4*>(&Dl[jrow * ND + (((9 + 2 * kg) ^ (il & 7)) << 2)]);
                const bf16x8 cb0 = cvt8(q0, q1);
                const bf16x8 cb1 = cvt8(q2, q3);
                const i32x4 ce = *reinterpret_cast<const i32x4*>(
                    &El[cb][il * 128 + (((jt * 4 + kg) ^ (il & 7)) << 2)]);

                f32x4 acc[NT];
                #pragma unroll
                for (int t = 0; t < NT; ++t) {
                    acc[t] = (f32x4){0.f, 0.f, 0.f, 0.f};
                    // A = dst rows (m=j), B = P (n=i): lane holds j=kg*4+r, i=il
                    acc[t] = __builtin_amdgcn_mfma_f32_16x16x32_bf16(cb0, pa[t][0], acc[t], 0, 0, 0);
                    acc[t] = __builtin_amdgcn_mfma_f32_16x16x32_bf16(cb1, pa[t][1], acc[t], 0, 0, 0);
                }

                f32x4 o;
                #pragma unroll
                for (int r = 0; r < 4; ++r) {
                    const int ev = ce[r];
                    float x;
                    if (ev < 0) { x = -1e10f; }
                    else {
                        x = (ev == 0) ? acc[0][r]
                          : (ev == 1) ? acc[1][r]
                          : (ev == 2) ? acc[2][r]
                          : (ev == 3) ? acc[3][r]
                          :             acc[4][r];
                    }
                    o[r] = (x >= 0.f) ? x : 0.2f * x;
                }
                *reinterpret_cast<f32x4*>(obase + jt * 16 + kg * 4) = o;
            }
        }

        // e) barrier: P/S[cb]/E[cb] reads done before next iter overwrites
        __syncthreads();
    }
}

// ---------------- fallback (ws too small): fused 1-wave kernel, araw path ----------------
__global__ __launch_bounds__(64, 3) void mhea_fused_fallback(
    const float* __restrict__ src, const float* __restrict__ dst,
    const float* __restrict__ araw, const int* __restrict__ edges,
    float* __restrict__ out)
{
    __shared__ __bf16 Plds[NT * 16 * 64];

    const int it = blockIdx.x;
    const int h  = blockIdx.y;
    const int b  = blockIdx.z;
    const int i0 = it * 16;

    const int l  = threadIdx.x & 63;
    const int il = l & 15;
    const int kg = l >> 4;

    const float* dbase = dst + (size_t)b * NN * HD + h * ND;
    const int*   erow  = edges + ((size_t)b * NN + i0 + il) * NN;
    const float* sbase = src + (size_t)(b * NN + i0 + il) * HD + h * ND;

    f32x4 s0 = *reinterpret_cast<const f32x4*>(sbase + kg * 8);
    f32x4 s1 = *reinterpret_cast<const f32x4*>(sbase + kg * 8 + 4);
    f32x4 s2 = *reinterpret_cast<const f32x4*>(sbase + 32 + kg * 8);
    f32x4 s3 = *reinterpret_cast<const f32x4*>(sbase + 36 + kg * 8);
    bf16x8 af0 = cvt8(s0, s1);
    bf16x8 af1 = cvt8(s2, s3);

    #pragma unroll
    for (int t = 0; t < NT; ++t) {
        #pragma unroll
        for (int et = 0; et < 4; ++et) {
            bf16x8 w0, w1;
            #pragma unroll
            for (int jj = 0; jj < 8; ++jj) {
                const int ee = et * 16 + il;
                w0[jj] = (__bf16)araw[((size_t)(h * ND + kg * 8 + jj) * ND + ee) * NT + t];
                w1[jj] = (__bf16)araw[((size_t)(h * ND + kg * 8 + jj + 32) * ND + ee) * NT + t];
            }
            f32x4 pacc = {0.f, 0.f, 0.f, 0.f};
            pacc = __builtin_amdgcn_mfma_f32_16x16x32_bf16(w0, af0, pacc, 0, 0, 0);
            pacc = __builtin_amdgcn_mfma_f32_16x16x32_bf16(w1, af1, pacc, 0, 0, 0);
            bf16x4 pk;
            pk[0] = (__bf16)pacc[0];
            pk[1] = (__bf16)pacc[1];
            pk[2] = (__bf16)pacc[2];
            pk[3] = (__bf16)pacc[3];
            const int elem = (et * 16 + kg * 4) ^ ((il & 7) << 3);
            *reinterpret_cast<bf16x4*>(&Plds[t * 1024 + il * 64 + elem]) = pk;
        }
    }

    bf16x8 pa[NT][2];
    #pragma unroll
    for (int t = 0; t < NT; ++t) {
        #pragma unroll
        for (int ks = 0; ks < 2; ++ks) {
            const int elem = (ks * 32 + kg * 8) ^ ((il & 7) << 3);
            pa[t][ks] = *reinterpret_cast<const bf16x8*>(&Plds[t * 1024 + il * 64 + elem]);
        }
    }

    float* obase = out + (((size_t)(b * NH + h)) * NN + i0 + il) * NN;

    for (int jt = 0; jt < 16; ++jt) {
        const float* np = dbase + (size_t)(jt * 16 + il) * HD + kg * 8;
        f32x4 d0 = *reinterpret_cast<const f32x4*>(np);
        f32x4 d1 = *reinterpret_cast<const f32x4*>(np + 4);
        f32x4 d2 = *reinterpret_cast<const f32x4*>(np + 32);
        f32x4 d3 = *reinterpret_cast<const f32x4*>(np + 36);
        i32x4 ce = *reinterpret_cast<const i32x4*>(erow + jt * 16 + kg * 4);
        const bf16x8 cb0 = cvt8(d0, d1);
        const bf16x8 cb1 = cvt8(d2, d3);
        f32x4 acc[NT];
        #pragma unroll
        for (int t = 0; t < NT; ++t) {
            acc[t] = (f32x4){0.f, 0.f, 0.f, 0.f};
            acc[t] = __builtin_amdgcn_mfma_f32_16x16x32_bf16(cb0, pa[t][0], acc[t], 0, 0, 0);
            acc[t] = __builtin_amdgcn_mfma_f32_16x16x32_bf16(cb1, pa[t][1], acc[t], 0, 0, 0);
        }
        f32x4 o;
        #pragma unroll
        for (int r = 0; r < 4; ++r) {
            const int ev = ce[r];
            float x;
            if (ev < 0) { x = -1e10f; }
            else {
                x = (ev == 0) ? acc[0][r]
                  : (ev == 1) ? acc[1][r]
                  : (ev == 2) ? acc[2][r]
                  : (ev == 3) ? acc[3][r]
                  :             acc[4][r];
            }
            o[r] = (x >= 0.f) ? x : 0.2f * x;
        }
        *reinterpret_cast<f32x4*>(obase + jt * 16 + kg * 4) = o;
    }
}

extern "C" void kernel_launch(void* const* d_in, const int* in_sizes, int n_in,
                              void* d_out, int out_size, void* d_ws, size_t ws_size,
                              hipStream_t stream) {
    const float* src   = (const float*)d_in[0];
    const float* dst   = (const float*)d_in[1];
    const float* a     = (const float*)d_in[2];
    const int*   edges = (const int*)d_in[3];
    float* out = (float*)d_out;

    const size_t wt_bytes = (size_t)NH * NT * ND * ND * sizeof(__bf16);  // 320 KB

    if (ws_size >= wt_bytes) {
        __bf16* wt = (__bf16*)d_ws;
        const int total = NH * ND * ND * NT;
        prep_w_kernel<<<(total + 255) / 256, 256, 0, stream>>>(a, wt);
        mhea_fused<<<256, 256, 0, stream>>>(src, dst, wt, edges, out);
    } else {
        mhea_fused_fallback<<<dim3(NN / 16, NH, NB), 64, 0, stream>>>(
            src, dst, a, edges, out);
    }
}

// Round 14
// 37.447 us; speedup vs baseline: 1.2014x; 1.2014x over previous
//
#include <hip/hip_runtime.h>
#include <hip/hip_bf16.h>

#define NB 16
#define NN 256
#define NH 8
#define ND 64
#define NT 5
#define HD 512   // NH*ND

typedef __bf16 bf16x8 __attribute__((ext_vector_type(8)));
typedef __bf16 bf16x4 __attribute__((ext_vector_type(4)));
typedef float  f32x4  __attribute__((ext_vector_type(4)));
typedef int    i32x4  __attribute__((ext_vector_type(4)));

__device__ __forceinline__ bf16x8 cvt8(f32x4 a, f32x4 b) {
    bf16x8 r;
    r[0] = (__bf16)a[0]; r[1] = (__bf16)a[1]; r[2] = (__bf16)a[2]; r[3] = (__bf16)a[3];
    r[4] = (__bf16)b[0]; r[5] = (__bf16)b[1]; r[6] = (__bf16)b[2]; r[7] = (__bf16)b[3];
    return r;
}

// fire-and-forget global->LDS: lane l writes LDS[base + l*16]; src addr is per-lane.
__device__ __forceinline__ void stage16(const void* g, void* l) {
    __builtin_amdgcn_global_load_lds(
        (const __attribute__((address_space(1))) void*)g,
        (__attribute__((address_space(3))) void*)l,
        16, 0, 0);
}

// Transpose a[(h*64+dd)*64*5 + e*5 + t] (fp32) -> wt[h][t][e][dd] (bf16).
__global__ void prep_w_kernel(const float* __restrict__ a, __bf16* __restrict__ wt) {
    int idx = blockIdx.x * 256 + threadIdx.x;
    if (idx >= NH * ND * ND * NT) return;
    int t  = idx % NT;
    int e  = (idx / NT) % ND;
    int dd = (idx / (NT * ND)) % ND;
    int h  = idx / (NT * ND * ND);
    wt[(((h * NT + t) * ND + e) * ND) + dd] = (__bf16)a[idx];
}

// ================= k1: T[b,h,t,i,e] = sum_dd src[b,i,h,dd] * W[h,dd,e,t] =================
// Block = (b,h,t,i-half). DMA-staged inputs; T written via LDS repack -> coalesced 1KB rows.
__global__ __launch_bounds__(256, 3) void k1_transform(
    const float* __restrict__ src, const __bf16* __restrict__ wt,
    __bf16* __restrict__ T)
{
    // W: rows e(64) x 128B, 16B-chunk c holds global chunk c^(e&7)     (8 KB)
    __shared__ alignas(16) __bf16 Wl[ND * ND];
    // S: rows i(128) x 256B, 16B-chunk c holds global chunk c^(i&7)    (32 KB)
    // ... later reused (first 16 KB) as P repack buffer: rows i(128) x 128B bf16,
    //     16B-chunk c holds output chunk c^(i&7)
    __shared__ alignas(16) float  Sl[128 * ND];

    const int bid = blockIdx.x;
    const int wg  = (bid & 7) * 160 + (bid >> 3);   // bijective, 1280 = 8*160
    const int t   = wg % NT;
    const int u   = wg / NT;      // 0..255
    const int ih  = u & 1;
    const int h   = (u >> 1) & 7;
    const int b   = u >> 4;

    const int tid = threadIdx.x;
    const int w   = tid >> 6;
    const int l   = tid & 63;
    const int il  = l & 15;
    const int kg  = l >> 4;

    // ---- DMA staging (pre-swizzled source, linear LDS dest) ----
    const __bf16* wgp = wt + (size_t)((h * NT + t) * ND) * ND;
    #pragma unroll
    for (int k = 0; k < 2; ++k) {            // W: 8 x 1KB
        const int idx = w * 2 + k;
        const int e   = idx * 8 + (l >> 3);
        const int c   = (l & 7) ^ (e & 7);
        stage16(wgp + (size_t)e * ND + c * 8, &Wl[idx * 8 * ND]);
    }
    #pragma unroll
    for (int k = 0; k < 8; ++k) {            // S: 32 x 1KB
        const int idx = w * 8 + k;
        const int ii  = idx * 4 + (l >> 4);
        const int c   = (l & 15) ^ (ii & 7);
        stage16(src + ((size_t)(b * NN + ih * 128 + ii)) * HD + h * ND + c * 4,
                &Sl[idx * 4 * ND]);
    }

    __syncthreads();   // vmcnt(0) drain = staging fence

    // A-frags (W rows, e = et*16+il, k-elems ks*32+kg*8..+7)
    bf16x8 af[4][2];
    #pragma unroll
    for (int et = 0; et < 4; ++et)
        #pragma unroll
        for (int ks = 0; ks < 2; ++ks)
            af[et][ks] = *reinterpret_cast<const bf16x8*>(
                &Wl[(et * 16 + il) * ND + (((ks * 4 + kg) ^ (il & 7)) << 3)]);

    // compute all results into registers (no stores yet)
    bf16x4 pk[2][4];
    #pragma unroll
    for (int it2 = 0; it2 < 2; ++it2) {
        const int iloc = (w * 2 + it2) * 16 + il;
        f32x4 f00 = *reinterpret_cast<const f32x4*>(&Sl[iloc * ND + (((2 * kg + 0) ^ (il & 7)) << 2)]);
        f32x4 f01 = *reinterpret_cast<const f32x4*>(&Sl[iloc * ND + (((2 * kg + 1) ^ (il & 7)) << 2)]);
        f32x4 f10 = *reinterpret_cast<const f32x4*>(&Sl[iloc * ND + (((8 + 2 * kg) ^ (il & 7)) << 2)]);
        f32x4 f11 = *reinterpret_cast<const f32x4*>(&Sl[iloc * ND + (((9 + 2 * kg) ^ (il & 7)) << 2)]);
        bf16x8 bf0 = cvt8(f00, f01);
        bf16x8 bf1 = cvt8(f10, f11);
        #pragma unroll
        for (int et = 0; et < 4; ++et) {
            // A = W^T rows (m=e), B = src (n=i): lane holds e=et*16+kg*4+r, i=il
            f32x4 pacc = {0.f, 0.f, 0.f, 0.f};
            pacc = __builtin_amdgcn_mfma_f32_16x16x32_bf16(af[et][0], bf0, pacc, 0, 0, 0);
            pacc = __builtin_amdgcn_mfma_f32_16x16x32_bf16(af[et][1], bf1, pacc, 0, 0, 0);
            pk[it2][et][0] = (__bf16)pacc[0];
            pk[it2][et][1] = (__bf16)pacc[1];
            pk[it2][et][2] = (__bf16)pacc[2];
            pk[it2][et][3] = (__bf16)pacc[3];
        }
    }

    __syncthreads();   // all Sl reads complete before repack overwrites

    // repack: P rows i(128) x 128B bf16 into Sl[0..16KB), swizzled by (i&7)
    __bf16* Pb = reinterpret_cast<__bf16*>(Sl);
    #pragma unroll
    for (int it2 = 0; it2 < 2; ++it2) {
        const int iloc = (w * 2 + it2) * 16 + il;
        #pragma unroll
        for (int et = 0; et < 4; ++et) {
            const int e0 = et * 16 + kg * 4;
            *reinterpret_cast<bf16x4*>(&Pb[iloc * ND + (e0 ^ ((iloc & 7) << 3))]) = pk[it2][et];
        }
    }

    __syncthreads();   // repack visible

    // coalesced store: 16 x 1KB (4/wave); block's 128 rows are contiguous in T
    __bf16* Tbase = T + (((size_t)(b * NH + h) * NT + t) * NN + ih * 128) * ND;
    #pragma unroll
    for (int k = 0; k < 4; ++k) {
        const int idx = w * 4 + k;               // 0..15
        const int r   = idx * 8 + (l >> 3);      // row 0..127
        const int c   = l & 7;                   // global 16B chunk
        const f32x4 v = *reinterpret_cast<const f32x4*>(
            &Pb[r * ND + ((c ^ (r & 7)) << 3)]);
        *reinterpret_cast<f32x4*>(Tbase + (size_t)r * ND + c * 8) = v;
    }
}

// ================= k2: S[i,j] = leaky(mask(select_t(T_t[i,:] . dst[j,:]))) =================
// Block = (b,h,32i,128j): dst tile staged ONCE per 2 i-tiles. Single barrier.
__global__ __launch_bounds__(256, 2) void k2_scores(
    const __bf16* __restrict__ T, const float* __restrict__ dst,
    const int* __restrict__ edges, float* __restrict__ out)
{
    // T: [it2][row=(t*16+i)(80) x 128B], chunk c holds global c^(row&7)  (20 KB)
    __shared__ alignas(16) __bf16 Tl[2 * NT * 16 * ND];
    // D: rows j(128) x 256B, chunk c holds global c^(j&7)                (32 KB)
    __shared__ alignas(16) float  Dl[128 * ND];
    // E: [it2][i(16) x 512B], chunk c holds global c^(i&7)               (16 KB)
    __shared__ alignas(16) int    El[2 * 16 * 128];

    const int bid = blockIdx.x;
    const int wg  = (bid & 7) * 256 + (bid >> 3);   // bijective, 2048 = 8*256
    const int b   = wg >> 7;
    const int rem = wg & 127;
    const int h   = rem >> 4;
    const int rm2 = rem & 15;
    const int ip  = rm2 >> 1;      // i-pair 0..7
    const int jh  = rm2 & 1;
    const int i0  = ip * 32;
    const int j0  = jh * 128;

    const int tid = threadIdx.x;
    const int w   = tid >> 6;
    const int l   = tid & 63;
    const int il  = l & 15;
    const int kg  = l >> 4;

    // ---- DMA staging (17 instrs/wave), one barrier ----
    const __bf16* Tg = T + ((size_t)(b * NH + h) * NT) * NN * ND;
    #pragma unroll
    for (int k = 0; k < 5; ++k) {            // T: 20 x 1KB
        const int idx  = w * 5 + k;          // 0..19
        const int it2  = idx / 10;
        const int sub  = idx % 10;
        const int r    = sub * 8 + (l >> 3); // 0..79 = t*16+iloc
        const int tt   = r >> 4;
        const int iloc = r & 15;
        const int c    = (l & 7) ^ (r & 7);
        stage16(Tg + ((size_t)tt * NN + i0 + it2 * 16 + iloc) * ND + c * 8,
                &Tl[idx * 512]);
    }
    #pragma unroll
    for (int k = 0; k < 8; ++k) {            // D: 32 x 1KB
        const int idx  = w * 8 + k;
        const int jloc = idx * 4 + (l >> 4);
        const int c    = (l & 15) ^ (jloc & 7);
        stage16(dst + ((size_t)(b * NN + j0 + jloc)) * HD + h * ND + c * 4,
                &Dl[idx * 256]);
    }
    #pragma unroll
    for (int k = 0; k < 4; ++k) {            // E: 16 x 1KB
        const int idx = w * 4 + k;           // 0..15
        const int it2 = idx >> 3;
        const int sub = idx & 7;
        const int row = sub * 2 + (l >> 5);  // 0..15
        const int c   = (l & 31) ^ (row & 7);
        stage16(edges + ((size_t)(b * NN + i0 + it2 * 16 + row)) * NN + j0 + c * 4,
                &El[idx * 256]);
    }

    __syncthreads();   // vmcnt(0) drain = staging fence

    #pragma unroll
    for (int it2 = 0; it2 < 2; ++it2) {
        // B-frags: T row i=il of this i-tile
        bf16x8 pa[NT][2];
        #pragma unroll
        for (int t = 0; t < NT; ++t)
            #pragma unroll
            for (int ks = 0; ks < 2; ++ks)
                pa[t][ks] = *reinterpret_cast<const bf16x8*>(
                    &Tl[it2 * 5120 + (t * 16 + il) * ND + (((ks * 4 + kg) ^ (il & 7)) << 3)]);

        float* obase = out + ((size_t)(b * NH + h) * NN + i0 + it2 * 16 + il) * NN + j0;

        #pragma unroll
        for (int jt2 = 0; jt2 < 2; ++jt2) {
            const int jt   = w * 2 + jt2;    // local j-tile 0..7
            const int jrow = jt * 16 + il;
            f32x4 q0 = *reinterpret_cast<const f32x4*>(&Dl[jrow * ND + (((2 * kg + 0) ^ (il & 7)) << 2)]);
            f32x4 q1 = *reinterpret_cast<const f32x4*>(&Dl[jrow * ND + (((2 * kg + 1) ^ (il & 7)) << 2)]);
            f32x4 q2 = *reinterpret_cast<const f32x4*>(&Dl[jrow * ND + (((8 + 2 * kg) ^ (il & 7)) << 2)]);
            f32x4 q3 = *reinterpret_cast<const f32x4*>(&Dl[jrow * ND + (((9 + 2 * kg) ^ (il & 7)) << 2)]);
            const bf16x8 cb0 = cvt8(q0, q1);
            const bf16x8 cb1 = cvt8(q2, q3);
            const i32x4 ce = *reinterpret_cast<const i32x4*>(
                &El[it2 * 2048 + il * 128 + (((jt * 4 + kg) ^ (il & 7)) << 2)]);

            f32x4 acc[NT];
            #pragma unroll
            for (int t = 0; t < NT; ++t) {
                acc[t] = (f32x4){0.f, 0.f, 0.f, 0.f};
                // A = dst rows (m=j), B = T (n=i): lane holds j=kg*4+r, i=il
                acc[t] = __builtin_amdgcn_mfma_f32_16x16x32_bf16(cb0, pa[t][0], acc[t], 0, 0, 0);
                acc[t] = __builtin_amdgcn_mfma_f32_16x16x32_bf16(cb1, pa[t][1], acc[t], 0, 0, 0);
            }

            f32x4 o;
            #pragma unroll
            for (int r = 0; r < 4; ++r) {
                const int ev = ce[r];
                float x;
                if (ev < 0) { x = -1e10f; }
                else {
                    x = (ev == 0) ? acc[0][r]
                      : (ev == 1) ? acc[1][r]
                      : (ev == 2) ? acc[2][r]
                      : (ev == 3) ? acc[3][r]
                      :             acc[4][r];
                }
                o[r] = (x >= 0.f) ? x : 0.2f * x;
            }
            *reinterpret_cast<f32x4*>(obase + jt * 16 + kg * 4) = o;
        }
    }
}

// ---------------- fallback (ws too small): fused 1-wave kernel, araw path ----------------
__global__ __launch_bounds__(64, 3) void mhea_fused_fallback(
    const float* __restrict__ src, const float* __restrict__ dst,
    const float* __restrict__ araw, const int* __restrict__ edges,
    float* __restrict__ out)
{
    __shared__ __bf16 Plds[NT * 16 * 64];

    const int it = blockIdx.x;
    const int h  = blockIdx.y;
    const int b  = blockIdx.z;
    const int i0 = it * 16;

    const int l  = threadIdx.x & 63;
    const int il = l & 15;
    const int kg = l >> 4;

    const float* dbase = dst + (size_t)b * NN * HD + h * ND;
    const int*   erow  = edges + ((size_t)b * NN + i0 + il) * NN;
    const float* sbase = src + (size_t)(b * NN + i0 + il) * HD + h * ND;

    f32x4 s0 = *reinterpret_cast<const f32x4*>(sbase + kg * 8);
    f32x4 s1 = *reinterpret_cast<const f32x4*>(sbase + kg * 8 + 4);
    f32x4 s2 = *reinterpret_cast<const f32x4*>(sbase + 32 + kg * 8);
    f32x4 s3 = *reinterpret_cast<const f32x4*>(sbase + 36 + kg * 8);
    bf16x8 af0 = cvt8(s0, s1);
    bf16x8 af1 = cvt8(s2, s3);

    #pragma unroll
    for (int t = 0; t < NT; ++t) {
        #pragma unroll
        for (int et = 0; et < 4; ++et) {
            bf16x8 w0, w1;
            #pragma unroll
            for (int jj = 0; jj < 8; ++jj) {
                const int ee = et * 16 + il;
                w0[jj] = (__bf16)araw[((size_t)(h * ND + kg * 8 + jj) * ND + ee) * NT + t];
                w1[jj] = (__bf16)araw[((size_t)(h * ND + kg * 8 + jj + 32) * ND + ee) * NT + t];
            }
            f32x4 pacc = {0.f, 0.f, 0.f, 0.f};
            pacc = __builtin_amdgcn_mfma_f32_16x16x32_bf16(w0, af0, pacc, 0, 0, 0);
            pacc = __builtin_amdgcn_mfma_f32_16x16x32_bf16(w1, af1, pacc, 0, 0, 0);
            bf16x4 pk;
            pk[0] = (__bf16)pacc[0];
            pk[1] = (__bf16)pacc[1];
            pk[2] = (__bf16)pacc[2];
            pk[3] = (__bf16)pacc[3];
            const int elem = (et * 16 + kg * 4) ^ ((il & 7) << 3);
            *reinterpret_cast<bf16x4*>(&Plds[t * 1024 + il * 64 + elem]) = pk;
        }
    }

    bf16x8 pa[NT][2];
    #pragma unroll
    for (int t = 0; t < NT; ++t) {
        #pragma unroll
        for (int ks = 0; ks < 2; ++ks) {
            const int elem = (ks * 32 + kg * 8) ^ ((il & 7) << 3);
            pa[t][ks] = *reinterpret_cast<const bf16x8*>(&Plds[t * 1024 + il * 64 + elem]);
        }
    }

    float* obase = out + (((size_t)(b * NH + h)) * NN + i0 + il) * NN;

    for (int jt = 0; jt < 16; ++jt) {
        const float* np = dbase + (size_t)(jt * 16 + il) * HD + kg * 8;
        f32x4 d0 = *reinterpret_cast<const f32x4*>(np);
        f32x4 d1 = *reinterpret_cast<const f32x4*>(np + 4);
        f32x4 d2 = *reinterpret_cast<const f32x4*>(np + 32);
        f32x4 d3 = *reinterpret_cast<const f32x4*>(np + 36);
        i32x4 ce = *reinterpret_cast<const i32x4*>(erow + jt * 16 + kg * 4);
        const bf16x8 cb0 = cvt8(d0, d1);
        const bf16x8 cb1 = cvt8(d2, d3);
        f32x4 acc[NT];
        #pragma unroll
        for (int t = 0; t < NT; ++t) {
            acc[t] = (f32x4){0.f, 0.f, 0.f, 0.f};
            acc[t] = __builtin_amdgcn_mfma_f32_16x16x32_bf16(cb0, pa[t][0], acc[t], 0, 0, 0);
            acc[t] = __builtin_amdgcn_mfma_f32_16x16x32_bf16(cb1, pa[t][1], acc[t], 0, 0, 0);
        }
        f32x4 o;
        #pragma unroll
        for (int r = 0; r < 4; ++r) {
            const int ev = ce[r];
            float x;
            if (ev < 0) { x = -1e10f; }
            else {
                x = (ev == 0) ? acc[0][r]
                  : (ev == 1) ? acc[1][r]
                  : (ev == 2) ? acc[2][r]
                  : (ev == 3) ? acc[3][r]
                  :             acc[4][r];
            }
            o[r] = (x >= 0.f) ? x : 0.2f * x;
        }
        *reinterpret_cast<f32x4*>(obase + jt * 16 + kg * 4) = o;
    }
}

extern "C" void kernel_launch(void* const* d_in, const int* in_sizes, int n_in,
                              void* d_out, int out_size, void* d_ws, size_t ws_size,
                              hipStream_t stream) {
    const float* src   = (const float*)d_in[0];
    const float* dst   = (const float*)d_in[1];
    const float* a     = (const float*)d_in[2];
    const int*   edges = (const int*)d_in[3];
    float* out = (float*)d_out;

    const size_t wt_bytes = (size_t)NH * NT * ND * ND * sizeof(__bf16);       // 320 KB
    const size_t t_off    = 1 << 20;                                          // 1 MB
    const size_t t_bytes  = (size_t)NB * NH * NT * NN * ND * sizeof(__bf16);  // 21 MB

    if (ws_size >= t_off + t_bytes && wt_bytes <= t_off) {
        __bf16* wt = (__bf16*)d_ws;
        __bf16* T  = (__bf16*)((char*)d_ws + t_off);
        const int total = NH * ND * ND * NT;
        prep_w_kernel<<<(total + 255) / 256, 256, 0, stream>>>(a, wt);
        k1_transform<<<1280, 256, 0, stream>>>(src, wt, T);
        k2_scores<<<2048, 256, 0, stream>>>(T, dst, edges, out);
    } else {
        mhea_fused_fallback<<<dim3(NN / 16, NH, NB), 64, 0, stream>>>(
            src, dst, a, edges, out);
    }
}